// Round 1
// baseline (1319.940 us; speedup 1.0000x reference)
//
#include <hip/hip_runtime.h>
#include <stdint.h>

// Problem dims
#define NROWS 65536
#define DCOL  480      // 128 + 3*64 + 5*32
#define RT    16       // rows per block

#define INV_S0 0.08838834764831845f   // 1/sqrt(128)
#define INV_S1 0.125f                  // 1/8
#define INV_S2 0.17677669529663687f    // 1/sqrt(32)
#define INV_T0 0.044194173824159216f   // 1/sqrt(512)
#define INV_T1 0.0625f                 // 1/16
#define INV_T2 0.08838834764831845f    // 1/sqrt(128)

__device__ __forceinline__ float bf_lo(uint32_t p){ return __builtin_bit_cast(float, p << 16); }
__device__ __forceinline__ float bf_hi(uint32_t p){ return __builtin_bit_cast(float, p & 0xFFFF0000u); }
__device__ __forceinline__ uint16_t f2bf(float x){
  uint32_t u = __builtin_bit_cast(uint32_t, x);
  return (uint16_t)((u + 0x8000u) >> 16);
}
__device__ __forceinline__ uint32_t pack2bf(float a, float b){
  return (uint32_t)f2bf(a) | ((uint32_t)f2bf(b) << 16);
}

__global__ __launch_bounds__(256, 2)
void ffn_fused(const float* __restrict__ x,  const float* __restrict__ nw0,
               const float* __restrict__ nb0,const float* __restrict__ nw1,
               const float* __restrict__ nw2,const float* __restrict__ W0,
               const float* __restrict__ b0, const float* __restrict__ W1,
               const float* __restrict__ W2, const float* __restrict__ V0,
               const float* __restrict__ c0, const float* __restrict__ V1,
               const float* __restrict__ V2, const float* __restrict__ alpha,
               float* __restrict__ out)
{
  // y layout per row: [0,128) y0 ; [128,320) y1T (m*64+u, m-major) ; [320,480) y2T (m*32+u)
  __shared__ __align__(16) float    ys[RT][484];      // 30976 B (stride 484 keeps float4 align)
  __shared__ __align__(16) uint32_t sbuf[RT][256];    // 16384 B: s (bf16 pairs) / z-stage / scratch
  __shared__ __align__(16) uint32_t gbuf[RT][192];    // 12288 B: g (bf16 pairs)

  const int t    = threadIdx.x;
  const int row0 = blockIdx.x * RT;
  const float ta = tanhf(alpha[0]);

  // ---------------- Phase 1: norms -> ys ----------------
  {
    const int wave = t >> 6, lane = t & 63;
    for (int rr = 0; rr < 4; ++rr){
      const int r = wave*4 + rr;
      const float* xr = x + (size_t)(row0 + r)*DCOL;
      float xv[8];
      #pragma unroll
      for (int i=0;i<8;++i){ const int e = lane + i*64; xv[i] = (e < DCOL) ? xr[e] : 0.f; }
      float s0  = xv[0] + xv[1];
      float s0q = xv[0]*xv[0] + xv[1]*xv[1];
      float q1  = xv[2]*xv[2] + xv[3]*xv[3] + xv[4]*xv[4];
      float q2  = xv[5]*xv[5] + xv[6]*xv[6] + xv[7]*xv[7];
      #pragma unroll
      for (int off=32; off>0; off>>=1){
        s0  += __shfl_xor(s0,  off);
        s0q += __shfl_xor(s0q, off);
        q1  += __shfl_xor(q1,  off);
        q2  += __shfl_xor(q2,  off);
      }
      const float mu   = s0 * (1.f/128.f);
      const float var  = s0q * (1.f/128.f) - mu*mu;
      const float rstd = rsqrtf(var + 1e-8f);
      const float inv  = rsqrtf(0.5f*(q1*(1.f/192.f) + q2*(1.f/160.f)) + 1e-8f);
      #pragma unroll
      for (int i=0;i<8;++i){
        const int e = lane + i*64;
        if (e < 128){
          ys[r][e] = (xv[i]-mu)*rstd*nw0[e] + nb0[e];
        } else if (e < 320){
          const int d = e - 128; const int u = d/3, mm = d - 3*u;
          ys[r][128 + mm*64 + u] = xv[i]*inv*nw1[u];
        } else if (e < DCOL){
          const int d = e - 320; const int u = d/5, mm = d - 5*u;
          ys[r][320 + mm*32 + u] = xv[i]*inv*nw2[u];
        }
      }
    }
  }
  __syncthreads();

  // ---------------- Phase 2: h0 = y0@W0/S0 + b0 -> silu/sigmoid -> sbuf/gbuf ----------------
  if (t < 224){
    const int j0 = t*4;
    const float4 b4 = *(const float4*)(b0 + j0);
    #pragma unroll 1
    for (int half=0; half<2; ++half){
      const int rb = half*8;
      float acc[8][4];
      #pragma unroll
      for (int r=0;r<8;++r){ acc[r][0]=0.f; acc[r][1]=0.f; acc[r][2]=0.f; acc[r][3]=0.f; }
      for (int k4=0; k4<32; ++k4){
        const float4 w0v = *(const float4*)(W0 + (size_t)(k4*4+0)*896 + j0);
        const float4 w1v = *(const float4*)(W0 + (size_t)(k4*4+1)*896 + j0);
        const float4 w2v = *(const float4*)(W0 + (size_t)(k4*4+2)*896 + j0);
        const float4 w3v = *(const float4*)(W0 + (size_t)(k4*4+3)*896 + j0);
        #pragma unroll
        for (int r=0;r<8;++r){
          const float4 yv = *(const float4*)&ys[rb+r][k4*4];
          acc[r][0] += yv.x*w0v.x + yv.y*w1v.x + yv.z*w2v.x + yv.w*w3v.x;
          acc[r][1] += yv.x*w0v.y + yv.y*w1v.y + yv.z*w2v.y + yv.w*w3v.y;
          acc[r][2] += yv.x*w0v.z + yv.y*w1v.z + yv.z*w2v.z + yv.w*w3v.z;
          acc[r][3] += yv.x*w0v.w + yv.y*w1v.w + yv.z*w2v.w + yv.w*w3v.w;
        }
      }
      #pragma unroll
      for (int r=0;r<8;++r){
        float h0v[4], sg[4];
        h0v[0] = acc[r][0]*INV_S0 + b4.x;
        h0v[1] = acc[r][1]*INV_S0 + b4.y;
        h0v[2] = acc[r][2]*INV_S0 + b4.z;
        h0v[3] = acc[r][3]*INV_S0 + b4.w;
        #pragma unroll
        for (int c=0;c<4;++c) sg[c] = 1.f/(1.f + expf(-h0v[c]));
        if (j0 < 512){
          sbuf[rb+r][(j0>>1)  ] = pack2bf(h0v[0]*sg[0], h0v[1]*sg[1]);
          sbuf[rb+r][(j0>>1)+1] = pack2bf(h0v[2]*sg[2], h0v[3]*sg[3]);
        } else {
          const int gp = (j0-512)>>1;
          gbuf[rb+r][gp  ] = pack2bf(sg[0], sg[1]);
          gbuf[rb+r][gp+1] = pack2bf(sg[2], sg[3]);
        }
      }
    }
  }
  __syncthreads();

  // ---------------- Phase 3: o0 = s@V0/T0 + c0 ; residual write cols [0,128) ----------------
  {
    const int mp = t & 127, jh = t >> 7;
    float acc0[16];
    #pragma unroll
    for (int r=0;r<16;++r) acc0[r]=0.f;
    for (int jj=0; jj<256; jj+=2){
      const int j = jh*256 + jj;
      const float v0 = V0[(size_t)j*128 + mp];
      const float v1 = V0[(size_t)j*128 + 128 + mp];
      const int p = j>>1;
      #pragma unroll
      for (int r=0;r<16;++r){
        const uint32_t pk = sbuf[r][p];
        acc0[r] += bf_lo(pk)*v0 + bf_hi(pk)*v1;
      }
    }
    __syncthreads();
    float* scr = (float*)&sbuf[0][0];
    if (jh==1){
      #pragma unroll
      for (int r=0;r<16;++r) scr[r*128+mp] = acc0[r];
    }
    __syncthreads();
    if (jh==0){
      #pragma unroll
      for (int r=0;r<16;++r){
        const float val = (acc0[r] + scr[r*128+mp])*INV_T0 + c0[mp];
        const size_t idx = (size_t)(row0+r)*DCOL + mp;
        out[idx] = x[idx] + ta*val;
      }
    }
    __syncthreads();
  }

  uint32_t* zzp = &sbuf[0][0];
  uint16_t* zz  = (uint16_t*)zzp;

  // ---------------- Phase 4: per m: h1 -> z1 -> o1 ; cols [128,320) ----------------
  #pragma unroll 1
  for (int m=0;m<3;++m){
    {
      const int w = t;                 // 0..255
      float acc1[16];
      #pragma unroll
      for (int r=0;r<16;++r) acc1[r]=0.f;
      for (int u4=0; u4<16; ++u4){
        const float wa = W1[(size_t)(u4*4+0)*256 + w];
        const float wb = W1[(size_t)(u4*4+1)*256 + w];
        const float wc = W1[(size_t)(u4*4+2)*256 + w];
        const float wd = W1[(size_t)(u4*4+3)*256 + w];
        #pragma unroll
        for (int r=0;r<16;++r){
          const float4 yv = *(const float4*)&ys[r][128 + m*64 + u4*4];
          acc1[r] += yv.x*wa + yv.y*wb + yv.z*wc + yv.w*wd;
        }
      }
      const int gpi = w>>1, gh = w&1;
      #pragma unroll
      for (int r=0;r<16;++r){
        const uint32_t gpk = gbuf[r][gpi];
        const float gv = gh ? bf_hi(gpk) : bf_lo(gpk);
        zz[r*256 + w] = f2bf(acc1[r]*INV_S1*gv);
      }
    }
    __syncthreads();
    {
      const int u = t & 63, rq = t >> 6;
      float acco[4] = {0.f,0.f,0.f,0.f};
      for (int ww=0; ww<256; ww+=2){
        const float v0 = V1[(size_t)ww*64 + u];
        const float v1 = V1[(size_t)ww*64 + 64 + u];
        #pragma unroll
        for (int rr=0; rr<4; ++rr){
          const int r = rq*4+rr;
          const uint32_t pk = zzp[r*128 + (ww>>1)];
          acco[rr] += bf_lo(pk)*v0 + bf_hi(pk)*v1;
        }
      }
      #pragma unroll
      for (int rr=0; rr<4; ++rr){
        const int r = rq*4+rr;
        const size_t idx = (size_t)(row0+r)*DCOL + 128 + u*3 + m;
        out[idx] = x[idx] + ta*(acco[rr]*INV_T1);
      }
    }
    __syncthreads();
  }

  // ---------------- Phase 5: per m: h2 -> z2 -> o2 ; cols [320,480) ----------------
  #pragma unroll 1
  for (int m=0;m<5;++m){
    {
      const int w = t & 127, rh = t >> 7;
      float acc2[8];
      #pragma unroll
      for (int rr=0;rr<8;++rr) acc2[rr]=0.f;
      for (int u4=0; u4<8; ++u4){
        const float wa = W2[(size_t)(u4*4+0)*128 + w];
        const float wb = W2[(size_t)(u4*4+1)*128 + w];
        const float wc = W2[(size_t)(u4*4+2)*128 + w];
        const float wd = W2[(size_t)(u4*4+3)*128 + w];
        #pragma unroll
        for (int rr=0;rr<8;++rr){
          const float4 yv = *(const float4*)&ys[rh*8+rr][320 + m*32 + u4*4];
          acc2[rr] += yv.x*wa + yv.y*wb + yv.z*wc + yv.w*wd;
        }
      }
      const int gpi = (256 + w)>>1, gh = w&1;
      #pragma unroll
      for (int rr=0;rr<8;++rr){
        const int r = rh*8+rr;
        const uint32_t gpk = gbuf[r][gpi];
        const float gv = gh ? bf_hi(gpk) : bf_lo(gpk);
        zz[r*128 + w] = f2bf(acc2[rr]*INV_S2*gv);
      }
    }
    __syncthreads();
    {
      const int u = t & 31, rq = t >> 5;
      float acco[2] = {0.f,0.f};
      for (int ww=0; ww<128; ww+=2){
        const float v0 = V2[(size_t)ww*32 + u];
        const float v1 = V2[(size_t)ww*32 + 32 + u];
        #pragma unroll
        for (int rr=0; rr<2; ++rr){
          const int r = rq*2+rr;
          const uint32_t pk = zzp[r*64 + (ww>>1)];
          acco[rr] += bf_lo(pk)*v0 + bf_hi(pk)*v1;
        }
      }
      #pragma unroll
      for (int rr=0; rr<2; ++rr){
        const int r = rq*2+rr;
        const size_t idx = (size_t)(row0+r)*DCOL + 320 + u*5 + m;
        out[idx] = x[idx] + ta*(acco[rr]*INV_T2);
      }
    }
    __syncthreads();
  }
}

extern "C" void kernel_launch(void* const* d_in, const int* in_sizes, int n_in,
                              void* d_out, int out_size, void* d_ws, size_t ws_size,
                              hipStream_t stream) {
  const float* x   = (const float*)d_in[0];
  const float* nw0 = (const float*)d_in[1];
  const float* nb0 = (const float*)d_in[2];
  const float* nw1 = (const float*)d_in[3];
  const float* nw2 = (const float*)d_in[4];
  const float* W0  = (const float*)d_in[5];
  const float* b0  = (const float*)d_in[6];
  const float* W1  = (const float*)d_in[7];
  const float* W2  = (const float*)d_in[8];
  const float* V0  = (const float*)d_in[9];
  const float* c0  = (const float*)d_in[10];
  const float* V1  = (const float*)d_in[11];
  const float* V2  = (const float*)d_in[12];
  const float* al  = (const float*)d_in[13];
  ffn_fused<<<dim3(NROWS/RT), dim3(256), 0, stream>>>(
      x, nw0, nb0, nw1, nw2, W0, b0, W1, W2, V0, c0, V1, V2, al, (float*)d_out);
}

// Round 2
// 512.052 us; speedup vs baseline: 2.5777x; 2.5777x over previous
//
#include <hip/hip_runtime.h>
#include <stdint.h>

#define NROWS 65536
#define DCOL  480      // 128 + 3*64 + 5*32
#define RT    16       // rows per block

#define INV_S0 0.08838834764831845f   // 1/sqrt(128)
#define INV_S1 0.125f                  // 1/8
#define INV_S2 0.17677669529663687f    // 1/sqrt(32)
#define INV_T0 0.044194173824159216f   // 1/sqrt(512)
#define INV_T1 0.0625f                 // 1/16
#define INV_T2 0.08838834764831845f    // 1/sqrt(128)

// d_ws element offsets (uint16_t units), fragment-linear transposed layouts Wt[n][k]
#define OFF_W0T 0         // [896][128]  (x INV_S0 folded)
#define OFF_W1T 114688    // [256][64]   (x INV_S1)
#define OFF_W2T 131072    // [128][32]   (x INV_S2)
#define OFF_V0T 135168    // [128][512]  (x INV_T0)
#define OFF_V1T 200704    // [64][256]   (x INV_T1)
#define OFF_V2T 217088    // [32][128]   (x INV_T2)
#define TOT_W   221184

typedef __attribute__((ext_vector_type(8))) short  short8;
typedef __attribute__((ext_vector_type(4))) float  floatx4;

__device__ __forceinline__ uint16_t f2bf(float x){
  uint32_t u = __builtin_bit_cast(uint32_t, x);
  return (uint16_t)((u + 0x8000u) >> 16);
}
__device__ __forceinline__ float bf2f(uint16_t h){
  return __builtin_bit_cast(float, (uint32_t)h << 16);
}

#define MFMA16(a,b,c) __builtin_amdgcn_mfma_f32_16x16x32_bf16((a),(b),(c),0,0,0)

// ---------------- weight conversion pre-pass: fp32 row-major -> bf16 Wt[n][k], scale folded
__global__ __launch_bounds__(256)
void convert_weights(const float* __restrict__ W0, const float* __restrict__ W1,
                     const float* __restrict__ W2, const float* __restrict__ V0,
                     const float* __restrict__ V1, const float* __restrict__ V2,
                     uint16_t* __restrict__ wt)
{
  const int tid = blockIdx.x*256 + threadIdx.x;
  if (tid >= TOT_W) return;
  if (tid < OFF_W1T){
    const int i = tid;            const int n = i>>7, k = i&127;
    wt[tid] = f2bf(W0[(size_t)k*896 + n] * INV_S0);
  } else if (tid < OFF_W2T){
    const int i = tid - OFF_W1T;  const int n = i>>6, k = i&63;
    wt[tid] = f2bf(W1[(size_t)k*256 + n] * INV_S1);
  } else if (tid < OFF_V0T){
    const int i = tid - OFF_W2T;  const int n = i>>5, k = i&31;
    wt[tid] = f2bf(W2[(size_t)k*128 + n] * INV_S2);
  } else if (tid < OFF_V1T){
    const int i = tid - OFF_V0T;  const int n = i>>9, k = i&511;
    wt[tid] = f2bf(V0[(size_t)k*128 + n] * INV_T0);
  } else if (tid < OFF_V2T){
    const int i = tid - OFF_V1T;  const int n = i>>8, k = i&255;
    wt[tid] = f2bf(V1[(size_t)k*64 + n] * INV_T1);
  } else {
    const int i = tid - OFF_V2T;  const int n = i>>7, k = i&127;
    wt[tid] = f2bf(V2[(size_t)k*32 + n] * INV_T2);
  }
}

// ---------------- fused main kernel: 16 rows / 4 waves / MFMA everywhere
__global__ __launch_bounds__(256, 3)
void ffn_mfma(const float* __restrict__ x,  const float* __restrict__ nw0,
              const float* __restrict__ nb0,const float* __restrict__ nw1,
              const float* __restrict__ nw2,const float* __restrict__ b0,
              const float* __restrict__ c0, const float* __restrict__ alpha,
              const uint16_t* __restrict__ wt, float* __restrict__ out)
{
  // all strides padded to stay 16B-aligned and spread LDS banks (stride%32dw==4)
  __shared__ __align__(16) uint16_t y0bf[16][136];     // A for h0  (K=128)
  __shared__ __align__(16) uint16_t y1bf[3][16][72];   // A for h1  (K=64)
  __shared__ __align__(16) uint16_t y2bf[5][16][40];   // A for h2  (K=32)
  __shared__ __align__(16) uint16_t gbf[16][392];      // gates (384)
  __shared__ __align__(16) uint16_t sbf[16][520];      // s (512); reused as z-stage later

  const int t      = threadIdx.x;
  const int wave   = t >> 6, lane = t & 63;
  const int lane16 = lane & 15, quad = lane >> 4;
  const int row0   = blockIdx.x * RT;
  const float ta   = tanhf(alpha[0]);

  // ---------- Phase 1: norms -> y (bf16, fragment-ready layouts) ----------
  {
    for (int rr = 0; rr < 4; ++rr){
      const int r = wave*4 + rr;
      const float* xr = x + (size_t)(row0 + r)*DCOL;
      float xv[8];
      #pragma unroll
      for (int i=0;i<8;++i){ const int e = lane + i*64; xv[i] = (e < DCOL) ? xr[e] : 0.f; }
      float s0  = xv[0] + xv[1];
      float s0q = xv[0]*xv[0] + xv[1]*xv[1];
      float q1  = xv[2]*xv[2] + xv[3]*xv[3] + xv[4]*xv[4];
      float q2  = xv[5]*xv[5] + xv[6]*xv[6] + xv[7]*xv[7];
      #pragma unroll
      for (int off=32; off>0; off>>=1){
        s0  += __shfl_xor(s0,  off);
        s0q += __shfl_xor(s0q, off);
        q1  += __shfl_xor(q1,  off);
        q2  += __shfl_xor(q2,  off);
      }
      const float mu   = s0 * (1.f/128.f);
      const float var  = s0q * (1.f/128.f) - mu*mu;
      const float rstd = rsqrtf(var + 1e-8f);
      const float inv  = rsqrtf(0.5f*(q1*(1.f/192.f) + q2*(1.f/160.f)) + 1e-8f);
      #pragma unroll
      for (int i=0;i<8;++i){
        const int e = lane + i*64;
        if (e < 128){
          y0bf[r][e] = f2bf((xv[i]-mu)*rstd*nw0[e] + nb0[e]);
        } else if (e < 320){
          const int d = e - 128; const int u = d/3, mm = d - 3*u;
          y1bf[mm][r][u] = f2bf(xv[i]*inv*nw1[u]);
        } else if (e < DCOL){
          const int d = e - 320; const int u = d/5, mm = d - 5*u;
          y2bf[mm][r][u] = f2bf(xv[i]*inv*nw2[u]);
        }
      }
    }
  }
  __syncthreads();

  // ---------- Phase 2: h0 = y0@W0 + b0 -> silu / sigmoid -> sbf / gbf ----------
  {
    short8 a0[4];
    #pragma unroll
    for (int kk=0; kk<4; ++kk)
      a0[kk] = *(const short8*)&y0bf[lane16][kk*32 + quad*8];
    const uint16_t* W0t = wt + OFF_W0T;
    #pragma unroll 1
    for (int tile = wave; tile < 56; tile += 4){
      const int n0 = tile*16;
      floatx4 acc = {0.f,0.f,0.f,0.f};
      #pragma unroll
      for (int kk=0; kk<4; ++kk){
        const short8 b = *(const short8*)(W0t + (size_t)(n0+lane16)*128 + kk*32 + quad*8);
        acc = MFMA16(a0[kk], b, acc);
      }
      const int col  = n0 + lane16;
      const float bias = b0[col];
      #pragma unroll
      for (int r2=0; r2<4; ++r2){
        const int row = quad*4 + r2;
        const float h  = acc[r2] + bias;
        const float sg = 1.f/(1.f + __expf(-h));
        if (col < 512) sbf[row][col]       = f2bf(h*sg);   // silu
        else           gbf[row][col - 512] = f2bf(sg);     // gate
      }
    }
  }
  __syncthreads();

  // ---------- Phase 3: o0 = s@V0 + c0 ; residual cols [0,128) ----------
  {
    const uint16_t* V0t = wt + OFF_V0T;
    const int n0a = wave*16, n0b = (wave+4)*16;
    floatx4 acc0 = {0.f,0.f,0.f,0.f}, acc1 = {0.f,0.f,0.f,0.f};
    #pragma unroll 2
    for (int kk=0; kk<16; ++kk){
      const short8 a  = *(const short8*)&sbf[lane16][kk*32 + quad*8];
      const short8 ba = *(const short8*)(V0t + (size_t)(n0a+lane16)*512 + kk*32 + quad*8);
      const short8 bb = *(const short8*)(V0t + (size_t)(n0b+lane16)*512 + kk*32 + quad*8);
      acc0 = MFMA16(a, ba, acc0);
      acc1 = MFMA16(a, bb, acc1);
    }
    #pragma unroll
    for (int tt=0; tt<2; ++tt){
      const int col = (tt ? n0b : n0a) + lane16;
      const float cc = c0[col];
      const floatx4 acc = tt ? acc1 : acc0;
      #pragma unroll
      for (int r2=0; r2<4; ++r2){
        const int row = quad*4 + r2;
        const size_t idx = (size_t)(row0+row)*DCOL + col;
        out[idx] = x[idx] + ta*(acc[r2] + cc);
      }
    }
  }
  __syncthreads();   // protects sbf reuse as z below

  uint16_t (*zbf1)[264] = (uint16_t (*)[264])&sbf[0][0];
  uint16_t (*zbf2)[136] = (uint16_t (*)[136])&sbf[0][0];

  // ---------- Phase 4: per m: h1 -> z1 -> o1 ; residual cols [128,320) ----------
  {
    const uint16_t* W1t = wt + OFF_W1T;
    const uint16_t* V1t = wt + OFF_V1T;
    #pragma unroll 1
    for (int m=0; m<3; ++m){
      {
        const short8 a0 = *(const short8*)&y1bf[m][lane16][quad*8];
        const short8 a1 = *(const short8*)&y1bf[m][lane16][32 + quad*8];
        #pragma unroll 1
        for (int tile = wave; tile < 16; tile += 4){
          const int n0 = tile*16;
          floatx4 acc = {0.f,0.f,0.f,0.f};
          const short8 b0f = *(const short8*)(W1t + (size_t)(n0+lane16)*64 + quad*8);
          const short8 b1f = *(const short8*)(W1t + (size_t)(n0+lane16)*64 + 32 + quad*8);
          acc = MFMA16(a0, b0f, acc);
          acc = MFMA16(a1, b1f, acc);
          const int col = n0 + lane16;
          #pragma unroll
          for (int r2=0; r2<4; ++r2){
            const int row = quad*4 + r2;
            const float g = bf2f(gbf[row][col]);        // g[:, :256]
            zbf1[row][col] = f2bf(acc[r2]*g);
          }
        }
      }
      __syncthreads();
      {
        const int n0 = wave*16;    // w in [0,64)
        floatx4 acc = {0.f,0.f,0.f,0.f};
        #pragma unroll
        for (int kk=0; kk<8; ++kk){
          const short8 a = *(const short8*)&zbf1[lane16][kk*32 + quad*8];
          const short8 b = *(const short8*)(V1t + (size_t)(n0+lane16)*256 + kk*32 + quad*8);
          acc = MFMA16(a, b, acc);
        }
        const int col = n0 + lane16;
        #pragma unroll
        for (int r2=0; r2<4; ++r2){
          const int row = quad*4 + r2;
          const size_t idx = (size_t)(row0+row)*DCOL + 128 + col*3 + m;
          out[idx] = x[idx] + ta*acc[r2];
        }
      }
      __syncthreads();
    }
  }

  // ---------- Phase 5: per m: h2 -> z2 -> o2 ; residual cols [320,480) ----------
  {
    const uint16_t* W2t = wt + OFF_W2T;
    const uint16_t* V2t = wt + OFF_V2T;
    #pragma unroll 1
    for (int m=0; m<5; ++m){
      {
        const short8 a0 = *(const short8*)&y2bf[m][lane16][quad*8];
        #pragma unroll 1
        for (int tile = wave; tile < 8; tile += 4){
          const int n0 = tile*16;
          floatx4 acc = {0.f,0.f,0.f,0.f};
          const short8 b = *(const short8*)(W2t + (size_t)(n0+lane16)*32 + quad*8);
          acc = MFMA16(a0, b, acc);
          const int col = n0 + lane16;
          #pragma unroll
          for (int r2=0; r2<4; ++r2){
            const int row = quad*4 + r2;
            const float g = bf2f(gbf[row][256 + col]);  // g[:, 256:384]
            zbf2[row][col] = f2bf(acc[r2]*g);
          }
        }
      }
      __syncthreads();
      if (wave < 2){
        const int n0 = wave*16;    // w in [0,32)
        floatx4 acc = {0.f,0.f,0.f,0.f};
        #pragma unroll
        for (int kk=0; kk<4; ++kk){
          const short8 a = *(const short8*)&zbf2[lane16][kk*32 + quad*8];
          const short8 b = *(const short8*)(V2t + (size_t)(n0+lane16)*128 + kk*32 + quad*8);
          acc = MFMA16(a, b, acc);
        }
        const int col = n0 + lane16;
        #pragma unroll
        for (int r2=0; r2<4; ++r2){
          const int row = quad*4 + r2;
          const size_t idx = (size_t)(row0+row)*DCOL + 320 + col*5 + m;
          out[idx] = x[idx] + ta*acc[r2];
        }
      }
      __syncthreads();
    }
  }
}

extern "C" void kernel_launch(void* const* d_in, const int* in_sizes, int n_in,
                              void* d_out, int out_size, void* d_ws, size_t ws_size,
                              hipStream_t stream) {
  const float* x   = (const float*)d_in[0];
  const float* nw0 = (const float*)d_in[1];
  const float* nb0 = (const float*)d_in[2];
  const float* nw1 = (const float*)d_in[3];
  const float* nw2 = (const float*)d_in[4];
  const float* W0  = (const float*)d_in[5];
  const float* b0  = (const float*)d_in[6];
  const float* W1  = (const float*)d_in[7];
  const float* W2  = (const float*)d_in[8];
  const float* V0  = (const float*)d_in[9];
  const float* c0  = (const float*)d_in[10];
  const float* V1  = (const float*)d_in[11];
  const float* V2  = (const float*)d_in[12];
  const float* al  = (const float*)d_in[13];
  uint16_t* wt = (uint16_t*)d_ws;   // needs 442368 B

  convert_weights<<<dim3((TOT_W + 255)/256), dim3(256), 0, stream>>>(
      W0, W1, W2, V0, V1, V2, wt);
  ffn_mfma<<<dim3(NROWS/RT), dim3(256), 0, stream>>>(
      x, nw0, nb0, nw1, nw2, b0, c0, al, wt, (float*)d_out);
}